// Round 8
// baseline (2026.147 us; speedup 1.0000x reference)
//
#include <hip/hip_runtime.h>
#include <hip/hip_bf16.h>

#define N_NODES 100000
#define IN_DIM 256
#define OUT_DIM 64
#define INV_KEEP 1.1111111111111112f  // 1/0.9

// row-bucket geometry: bucket = 256 consecutive rows; bucket range in the CSR
// array = [start[b*256], start[(b+1)*256]) -- partition appends here directly.
#define BROWS 256
#define NBUCKET ((N_NODES + BROWS - 1) / BROWS)   // 391
#define A_CAP 9728   // max records/bucket (mean 8184, sigma 90 -> +17 sigma)
#define X_CAP 5120   // mean ~3680, sigma 60 -> +24 sigma

// multi-block scan geometry: 4 elems/thread, 1024 elems/block
#define SCAN_PT 4
#define SCAN_BE (256 * SCAN_PT)                   // 1024

__device__ __forceinline__ int   ldnt (const int* p)   { return __builtin_nontemporal_load(p); }
__device__ __forceinline__ float ldntf(const float* p) { return __builtin_nontemporal_load(p); }

// ======================= histogram (plain, no slicing) =======================

__global__ __launch_bounds__(256) void hist_kernel(
    const int* __restrict__ rows, const int* __restrict__ keep,
    int* __restrict__ counts, int nnz)
{
    int i = (int)(blockIdx.x * blockDim.x + threadIdx.x);
    int stride = (int)(gridDim.x * blockDim.x);
    if (keep) {
        for (int e = i; e < nnz; e += stride)
            if (ldnt(keep + e) != 0) atomicAdd(&counts[ldnt(rows + e)], 1);
    } else {
        for (int e = i; e < nnz; e += stride)
            atomicAdd(&counts[ldnt(rows + e)], 1);
    }
}

// ---- 3-pass exclusive scan over two arrays (cx->sx, ca->sa) ----
__global__ __launch_bounds__(256) void scan_pass1_kernel(
    const int* __restrict__ cx, const int* __restrict__ ca,
    int* __restrict__ blocksums, int nb)
{
    const int arr = blockIdx.x / nb;
    const int b   = blockIdx.x % nb;
    const int* c  = arr ? ca : cx;
    const int t   = threadIdx.x;
    const int base = b * SCAN_BE + t * SCAN_PT;

    int s = 0;
#pragma unroll
    for (int k = 0; k < SCAN_PT; ++k) {
        int i = base + k;
        if (i < N_NODES) s += c[i];
    }
    __shared__ int lds[256];
    lds[t] = s;
    __syncthreads();
    for (int off = 128; off > 0; off >>= 1) {
        if (t < off) lds[t] += lds[t + off];
        __syncthreads();
    }
    if (t == 0) blocksums[blockIdx.x] = lds[0];
}

__global__ __launch_bounds__(256) void scan_pass2_kernel(
    int* __restrict__ blocksums, int nb)
{
    const int t = threadIdx.x;
    const int arr = t >> 7;
    const int b   = t & 127;
    __shared__ int lds[256];
    lds[t] = (b < nb) ? blocksums[arr * nb + b] : 0;
    __syncthreads();
    for (int off = 1; off <= 64; off <<= 1) {
        int v = ((t & 127) >= off) ? lds[t - off] : 0;
        __syncthreads();
        lds[t] += v;
        __syncthreads();
    }
    if (b < nb)
        blocksums[arr * nb + b] = (b > 0) ? lds[t - 1] : 0;  // exclusive
}

__global__ __launch_bounds__(256) void scan_pass3_kernel(
    const int* __restrict__ cx, int* __restrict__ sx,
    const int* __restrict__ ca, int* __restrict__ sa,
    const int* __restrict__ blocksums, int nb)
{
    const int arr = blockIdx.x / nb;
    const int b   = blockIdx.x % nb;
    const int* counts = arr ? ca : cx;
    int* start        = arr ? sa : sx;
    const int t = threadIdx.x;
    const int base = b * SCAN_BE + t * SCAN_PT;

    int vals[SCAN_PT];
    int s = 0;
#pragma unroll
    for (int k = 0; k < SCAN_PT; ++k) {
        int i = base + k;
        vals[k] = (i < N_NODES) ? counts[i] : 0;
        s += vals[k];
    }
    __shared__ int lds[256];
    lds[t] = s;
    __syncthreads();
    for (int off = 1; off <= 128; off <<= 1) {
        int v = (t >= off) ? lds[t - off] : 0;
        __syncthreads();
        lds[t] += v;
        __syncthreads();
    }
    int run = ((t > 0) ? lds[t - 1] : 0) + blocksums[blockIdx.x];
#pragma unroll
    for (int k = 0; k < SCAN_PT; ++k) {
        int i = base + k;
        if (i < N_NODES) {
            start[i] = run;
            run += vals[k];
            if (i == N_NODES - 1) start[N_NODES] = run;
        }
    }
}

// bucket append cursors = start[b*BROWS]
__global__ __launch_bounds__(512) void init_bcursor_kernel(
    const int* __restrict__ x_start, const int* __restrict__ a_start,
    int* __restrict__ bcx, int* __restrict__ bca)
{
    int i = threadIdx.x;
    for (; i < 2 * NBUCKET; i += 512) {
        if (i < NBUCKET) bcx[i] = x_start[i * BROWS];
        else             bca[i - NBUCKET] = a_start[(i - NBUCKET) * BROWS];
    }
}

// ======================= partition (bucket-append, narrow write front) =======================
// Write front = NBUCKET active lines (~25 KB) -> stays L2-resident, lines fill
// completely before eviction: no RFO, WRITE ~= payload.

__global__ __launch_bounds__(256) void partition_x_kernel(
    const float* __restrict__ xv, const int* __restrict__ xr,
    const int* __restrict__ xc, const int* __restrict__ keep,
    int* __restrict__ bcur, float2* __restrict__ out, int nnz)
{
    int i = (int)(blockIdx.x * blockDim.x + threadIdx.x);
    int stride = (int)(gridDim.x * blockDim.x);
    for (int e = i; e < nnz; e += stride) {
        if (ldnt(keep + e) == 0) continue;
        int r = ldnt(xr + e);
        int c = ldnt(xc + e);
        float v = ldntf(xv + e) * INV_KEEP;
        int pos = atomicAdd(&bcur[r >> 8], 1);
        out[pos] = make_float2(v, __uint_as_float(((unsigned)c << 8) | (unsigned)(r & (BROWS - 1))));
    }
}

__global__ __launch_bounds__(256) void partition_a_kernel(
    const float* __restrict__ av, const int* __restrict__ ar,
    const int* __restrict__ ac,
    int* __restrict__ bcur, float2* __restrict__ out, int nnz)
{
    int i = (int)(blockIdx.x * blockDim.x + threadIdx.x);
    int stride = (int)(gridDim.x * blockDim.x);
    for (int e = i; e < nnz; e += stride) {
        int r = ldnt(ar + e);
        int c = ldnt(ac + e);
        float v = ldntf(av + e);
        int pos = atomicAdd(&bcur[r >> 8], 1);
        out[pos] = make_float2(v, __uint_as_float(((unsigned)c << 8) | (unsigned)(r & (BROWS - 1))));
    }
}

// ======================= in-place per-bucket row-grouping =======================
// One block per bucket: load all records to LDS, then rewrite row-grouped
// (val, col) into the same global range. Reads complete before writes.

template <int CAP>
__global__ __launch_bounds__(256) void reorder_kernel(
    const int* __restrict__ start, float2* __restrict__ data)
{
    __shared__ float2 recs[CAP];
    __shared__ int curs[BROWS];
    const int b = blockIdx.x;
    const int brow0 = b * BROWS;
    const int rows_n = min(BROWS, N_NODES - brow0);
    const int base = start[brow0];
    int size = start[brow0 + rows_n] - base;
    if (size > CAP) size = CAP;   // +17..24 sigma guard; prevents corruption

    for (int r = threadIdx.x; r < rows_n; r += blockDim.x)
        curs[r] = start[brow0 + r];
    for (int i = threadIdx.x; i < size; i += blockDim.x)
        recs[i] = data[base + i];
    __syncthreads();
    for (int i = threadIdx.x; i < size; i += blockDim.x) {
        float2 rec = recs[i];
        unsigned u = __float_as_uint(rec.y);
        int row = (int)(u & (BROWS - 1));
        int col = (int)(u >> 8);
        int pos = atomicAdd(&curs[row], 1);
        data[pos] = make_float2(rec.x, __int_as_float(col));
    }
}

// ======================= SpMM (one wave per row, MLP-unrolled) =======================

__global__ __launch_bounds__(256) void spmm1_csr_kernel(
    const int* __restrict__ xs_start, const float2* __restrict__ xs,
    const float* __restrict__ W, __hip_bfloat16* __restrict__ h)
{
    const int wave = (int)((blockIdx.x * blockDim.x + threadIdx.x) >> 6);
    const int lane = threadIdx.x & 63;
    if (wave >= N_NODES) return;

    const int s = xs_start[wave];
    const int e = xs_start[wave + 1];
    float acc = 0.0f;
    int j = s;
    for (; j + 4 <= e; j += 4) {
        float2 p0 = xs[j + 0];
        float2 p1 = xs[j + 1];
        float2 p2 = xs[j + 2];
        float2 p3 = xs[j + 3];
        float g0 = W[__float_as_int(p0.y) * OUT_DIM + lane];
        float g1 = W[__float_as_int(p1.y) * OUT_DIM + lane];
        float g2 = W[__float_as_int(p2.y) * OUT_DIM + lane];
        float g3 = W[__float_as_int(p3.y) * OUT_DIM + lane];
        acc += p0.x * g0;
        acc += p1.x * g1;
        acc += p2.x * g2;
        acc += p3.x * g3;
    }
    for (; j < e; ++j) {
        float2 p = xs[j];
        acc += p.x * W[__float_as_int(p.y) * OUT_DIM + lane];
    }
    h[(size_t)wave * OUT_DIM + lane] = __float2bfloat16(acc);
}

__global__ __launch_bounds__(256) void spmm2_csr_kernel(
    const int* __restrict__ as_start, const float2* __restrict__ as,
    const __hip_bfloat16* __restrict__ h, float* __restrict__ out)
{
    const int wave = (int)((blockIdx.x * blockDim.x + threadIdx.x) >> 6);
    const int lane = threadIdx.x & 63;
    if (wave >= N_NODES) return;

    const int s = as_start[wave];
    const int e = as_start[wave + 1];
    float acc = 0.0f;
    int j = s;
    for (; j + 8 <= e; j += 8) {
        float2 p0 = as[j + 0];
        float2 p1 = as[j + 1];
        float2 p2 = as[j + 2];
        float2 p3 = as[j + 3];
        float2 p4 = as[j + 4];
        float2 p5 = as[j + 5];
        float2 p6 = as[j + 6];
        float2 p7 = as[j + 7];
        float g0 = __bfloat162float(h[(size_t)__float_as_int(p0.y) * OUT_DIM + lane]);
        float g1 = __bfloat162float(h[(size_t)__float_as_int(p1.y) * OUT_DIM + lane]);
        float g2 = __bfloat162float(h[(size_t)__float_as_int(p2.y) * OUT_DIM + lane]);
        float g3 = __bfloat162float(h[(size_t)__float_as_int(p3.y) * OUT_DIM + lane]);
        float g4 = __bfloat162float(h[(size_t)__float_as_int(p4.y) * OUT_DIM + lane]);
        float g5 = __bfloat162float(h[(size_t)__float_as_int(p5.y) * OUT_DIM + lane]);
        float g6 = __bfloat162float(h[(size_t)__float_as_int(p6.y) * OUT_DIM + lane]);
        float g7 = __bfloat162float(h[(size_t)__float_as_int(p7.y) * OUT_DIM + lane]);
        acc += p0.x * g0;
        acc += p1.x * g1;
        acc += p2.x * g2;
        acc += p3.x * g3;
        acc += p4.x * g4;
        acc += p5.x * g5;
        acc += p6.x * g6;
        acc += p7.x * g7;
    }
    for (; j < e; ++j) {
        float2 p = as[j];
        acc += p.x * __bfloat162float(h[(size_t)__float_as_int(p.y) * OUT_DIM + lane]);
    }
    out[(size_t)wave * OUT_DIM + lane] = acc > 0.0f ? acc : 0.0f;
}

// ======================= fallback (atomic) path =======================

__global__ __launch_bounds__(256) void spmm1_atomic_kernel(
    const float* __restrict__ x_vals, const int* __restrict__ x_rows,
    const int* __restrict__ x_cols, const int* __restrict__ keep,
    const float* __restrict__ W, float* __restrict__ h, int nnz)
{
    const int lane   = threadIdx.x & 63;
    const int group  = (int)((blockIdx.x * blockDim.x + threadIdx.x) >> 6);
    const int stride = (int)((gridDim.x * blockDim.x) >> 6);
    for (int e = group; e < nnz; e += stride) {
        float v = (keep[e] != 0) ? x_vals[e] * INV_KEEP : 0.0f;
        if (v != 0.0f)
            atomicAdd(&h[(size_t)x_rows[e] * OUT_DIM + lane],
                      v * W[x_cols[e] * OUT_DIM + lane]);
    }
}

__global__ __launch_bounds__(256) void spmm2_atomic_kernel(
    const float* __restrict__ adj_vals, const int* __restrict__ adj_rows,
    const int* __restrict__ adj_cols, const float* __restrict__ h,
    float* __restrict__ out, int nnz)
{
    const int lane   = threadIdx.x & 63;
    const int group  = (int)((blockIdx.x * blockDim.x + threadIdx.x) >> 6);
    const int stride = (int)((gridDim.x * blockDim.x) >> 6);
    for (int e = group; e < nnz; e += stride) {
        atomicAdd(&out[(size_t)adj_rows[e] * OUT_DIM + lane],
                  adj_vals[e] * h[(size_t)adj_cols[e] * OUT_DIM + lane]);
    }
}

__global__ __launch_bounds__(256) void relu_kernel(float* __restrict__ out, int n)
{
    int i = (int)(blockIdx.x * blockDim.x + threadIdx.x);
    if (i < n) {
        float v = out[i];
        out[i] = v > 0.0f ? v : 0.0f;
    }
}

// ======================= launch =======================

extern "C" void kernel_launch(void* const* d_in, const int* in_sizes, int n_in,
                              void* d_out, int out_size, void* d_ws, size_t ws_size,
                              hipStream_t stream)
{
    const float* x_vals   = (const float*)d_in[0];
    const int*   x_rows   = (const int*)d_in[1];
    const int*   x_cols   = (const int*)d_in[2];
    const float* adj_vals = (const float*)d_in[3];
    const int*   adj_rows = (const int*)d_in[4];
    const int*   adj_cols = (const int*)d_in[5];
    const float* W        = (const float*)d_in[6];
    const int*   keep     = (const int*)d_in[7];

    const int x_nnz = in_sizes[0];
    const int a_nnz = in_sizes[3];

    float* out = (float*)d_out;

    // workspace layout (8B-aligned chunks first)
    char* ws = (char*)d_ws;
    size_t off = 0;
    float2* xs = (float2*)(ws + off);            off += (size_t)x_nnz * 8;           // 12.8 MB
    float2* as = (float2*)(ws + off);            off += (size_t)a_nnz * 8;           // 25.6 MB
    __hip_bfloat16* hb = (__hip_bfloat16*)(ws + off); off += (size_t)N_NODES * OUT_DIM * 2; // 12.8 MB
    int* counts_x = (int*)(ws + off);            off += (size_t)N_NODES * 4;
    int* counts_a = (int*)(ws + off);            off += (size_t)N_NODES * 4;
    int* x_start  = (int*)(ws + off);            off += (size_t)(N_NODES + 1) * 4;
    int* a_start  = (int*)(ws + off);            off += (size_t)(N_NODES + 1) * 4;
    int* blocksums = (int*)(ws + off);           off += (size_t)2 * ((N_NODES + SCAN_BE - 1) / SCAN_BE) * 4;
    int* bcx = (int*)(ws + off);                 off += (size_t)NBUCKET * 4;
    int* bca = (int*)(ws + off);                 off += (size_t)NBUCKET * 4;
    const size_t needed = off;

    const int nb = (N_NODES + SCAN_BE - 1) / SCAN_BE;   // scan blocks per array (<=128)

    if (ws_size >= needed) {
        // -------- bucket-CSR path --------
        hipMemsetAsync(counts_x, 0, (size_t)2 * N_NODES * 4, stream);

        hist_kernel<<<1024, 256, 0, stream>>>(x_rows, keep, counts_x, x_nnz);
        hist_kernel<<<1024, 256, 0, stream>>>(adj_rows, (const int*)nullptr, counts_a, a_nnz);

        scan_pass1_kernel<<<2 * nb, 256, 0, stream>>>(counts_x, counts_a, blocksums, nb);
        scan_pass2_kernel<<<1, 256, 0, stream>>>(blocksums, nb);
        scan_pass3_kernel<<<2 * nb, 256, 0, stream>>>(counts_x, x_start, counts_a, a_start,
                                                      blocksums, nb);

        init_bcursor_kernel<<<1, 512, 0, stream>>>(x_start, a_start, bcx, bca);

        partition_x_kernel<<<2048, 256, 0, stream>>>(x_vals, x_rows, x_cols, keep,
                                                     bcx, xs, x_nnz);
        partition_a_kernel<<<2048, 256, 0, stream>>>(adj_vals, adj_rows, adj_cols,
                                                     bca, as, a_nnz);

        reorder_kernel<X_CAP><<<NBUCKET, 256, 0, stream>>>(x_start, xs);
        reorder_kernel<A_CAP><<<NBUCKET, 256, 0, stream>>>(a_start, as);

        const int blocks = (N_NODES * 64 + 255) / 256;  // one wave per row
        spmm1_csr_kernel<<<blocks, 256, 0, stream>>>(x_start, xs, W, hb);
        spmm2_csr_kernel<<<blocks, 256, 0, stream>>>(a_start, as, hb, out);
    } else {
        // -------- fallback: atomic path --------
        float* hf = (float*)d_ws;
        hipMemsetAsync(hf, 0, (size_t)N_NODES * OUT_DIM * 4, stream);
        hipMemsetAsync(out, 0, (size_t)out_size * 4, stream);
        spmm1_atomic_kernel<<<4096, 256, 0, stream>>>(x_vals, x_rows, x_cols, keep, W, hf, x_nnz);
        spmm2_atomic_kernel<<<4096, 256, 0, stream>>>(adj_vals, adj_rows, adj_cols, hf, out, a_nnz);
        relu_kernel<<<(out_size + 255) / 256, 256, 0, stream>>>(out, out_size);
    }
}

// Round 9
// 515.748 us; speedup vs baseline: 3.9286x; 3.9286x over previous
//
#include <hip/hip_runtime.h>
#include <hip/hip_bf16.h>

#define N_NODES 100000
#define IN_DIM 256
#define OUT_DIM 64
#define INV_KEEP 1.1111111111111112f  // 1/0.9

// row-bucket geometry: bucket = 256 consecutive rows; bucket range in the CSR
// array = [start[b*256], start[(b+1)*256]) -- partition appends here directly.
#define BROWS 256
#define NBUCKET ((N_NODES + BROWS - 1) / BROWS)   // 391
#define BCPAD 16     // pad bucket cursors to one 64B line each (atomic same-line serialization!)
#define A_CAP 9728   // max records/bucket (mean 8184, sigma 90 -> +17 sigma)
#define X_CAP 5120   // mean ~3680, sigma 60 -> +24 sigma

#define PART_BLOCKS 256   // partition blocks: few blocks => block-private write ranges

// multi-block scan geometry: 4 elems/thread, 1024 elems/block
#define SCAN_PT 4
#define SCAN_BE (256 * SCAN_PT)                   // 1024

__device__ __forceinline__ int   ldnt (const int* p)   { return __builtin_nontemporal_load(p); }
__device__ __forceinline__ float ldntf(const float* p) { return __builtin_nontemporal_load(p); }

// ======================= histogram =======================

__global__ __launch_bounds__(256) void hist_kernel(
    const int* __restrict__ rows, const int* __restrict__ keep,
    int* __restrict__ counts, int nnz)
{
    int i = (int)(blockIdx.x * blockDim.x + threadIdx.x);
    int stride = (int)(gridDim.x * blockDim.x);
    if (keep) {
        for (int e = i; e < nnz; e += stride)
            if (ldnt(keep + e) != 0) atomicAdd(&counts[ldnt(rows + e)], 1);
    } else {
        for (int e = i; e < nnz; e += stride)
            atomicAdd(&counts[ldnt(rows + e)], 1);
    }
}

// ---- 3-pass exclusive scan over two arrays (cx->sx, ca->sa) ----
__global__ __launch_bounds__(256) void scan_pass1_kernel(
    const int* __restrict__ cx, const int* __restrict__ ca,
    int* __restrict__ blocksums, int nb)
{
    const int arr = blockIdx.x / nb;
    const int b   = blockIdx.x % nb;
    const int* c  = arr ? ca : cx;
    const int t   = threadIdx.x;
    const int base = b * SCAN_BE + t * SCAN_PT;

    int s = 0;
#pragma unroll
    for (int k = 0; k < SCAN_PT; ++k) {
        int i = base + k;
        if (i < N_NODES) s += c[i];
    }
    __shared__ int lds[256];
    lds[t] = s;
    __syncthreads();
    for (int off = 128; off > 0; off >>= 1) {
        if (t < off) lds[t] += lds[t + off];
        __syncthreads();
    }
    if (t == 0) blocksums[blockIdx.x] = lds[0];
}

__global__ __launch_bounds__(256) void scan_pass2_kernel(
    int* __restrict__ blocksums, int nb)
{
    const int t = threadIdx.x;
    const int arr = t >> 7;
    const int b   = t & 127;
    __shared__ int lds[256];
    lds[t] = (b < nb) ? blocksums[arr * nb + b] : 0;
    __syncthreads();
    for (int off = 1; off <= 64; off <<= 1) {
        int v = ((t & 127) >= off) ? lds[t - off] : 0;
        __syncthreads();
        lds[t] += v;
        __syncthreads();
    }
    if (b < nb)
        blocksums[arr * nb + b] = (b > 0) ? lds[t - 1] : 0;  // exclusive
}

__global__ __launch_bounds__(256) void scan_pass3_kernel(
    const int* __restrict__ cx, int* __restrict__ sx,
    const int* __restrict__ ca, int* __restrict__ sa,
    const int* __restrict__ blocksums, int nb)
{
    const int arr = blockIdx.x / nb;
    const int b   = blockIdx.x % nb;
    const int* counts = arr ? ca : cx;
    int* start        = arr ? sa : sx;
    const int t = threadIdx.x;
    const int base = b * SCAN_BE + t * SCAN_PT;

    int vals[SCAN_PT];
    int s = 0;
#pragma unroll
    for (int k = 0; k < SCAN_PT; ++k) {
        int i = base + k;
        vals[k] = (i < N_NODES) ? counts[i] : 0;
        s += vals[k];
    }
    __shared__ int lds[256];
    lds[t] = s;
    __syncthreads();
    for (int off = 1; off <= 128; off <<= 1) {
        int v = (t >= off) ? lds[t - off] : 0;
        __syncthreads();
        lds[t] += v;
        __syncthreads();
    }
    int run = ((t > 0) ? lds[t - 1] : 0) + blocksums[blockIdx.x];
#pragma unroll
    for (int k = 0; k < SCAN_PT; ++k) {
        int i = base + k;
        if (i < N_NODES) {
            start[i] = run;
            run += vals[k];
            if (i == N_NODES - 1) start[N_NODES] = run;
        }
    }
}

// bucket append cursors (padded, one per 64B line) = start[b*BROWS]
__global__ __launch_bounds__(512) void init_bcursor_kernel(
    const int* __restrict__ x_start, const int* __restrict__ a_start,
    int* __restrict__ bcx, int* __restrict__ bca)
{
    int i = threadIdx.x;
    for (; i < 2 * NBUCKET; i += 512) {
        if (i < NBUCKET) bcx[i * BCPAD] = x_start[i * BROWS];
        else             bca[(i - NBUCKET) * BCPAD] = a_start[(i - NBUCKET) * BROWS];
    }
}

// ======================= partition: block-aggregated 2-pass bucket append =======================
// pass1: count chunk's bucket occupancy in LDS. reserve: 1 global atomic per
// (block,bucket) on padded cursors. pass2: place records into block-private
// contiguous ranges via LDS cursors. Write lines are filled by one block
// => no cross-XCD line ping-pong, minimal RFO.

__global__ __launch_bounds__(256) void partition_x_kernel(
    const float* __restrict__ xv, const int* __restrict__ xr,
    const int* __restrict__ xc, const int* __restrict__ keep,
    int* __restrict__ bcur, float2* __restrict__ out, int nnz)
{
    __shared__ int cnt[NBUCKET];
    const int chunk = (nnz + (int)gridDim.x - 1) / (int)gridDim.x;
    const int lo = (int)blockIdx.x * chunk;
    const int hi = min(lo + chunk, nnz);

    for (int k = threadIdx.x; k < NBUCKET; k += blockDim.x) cnt[k] = 0;
    __syncthreads();
    for (int e = lo + (int)threadIdx.x; e < hi; e += (int)blockDim.x)
        if (ldnt(keep + e) != 0) atomicAdd(&cnt[ldnt(xr + e) >> 8], 1);
    __syncthreads();
    for (int k = threadIdx.x; k < NBUCKET; k += blockDim.x) {
        int n = cnt[k];
        cnt[k] = (n > 0) ? atomicAdd(&bcur[k * BCPAD], n) : 0;
    }
    __syncthreads();
    for (int e = lo + (int)threadIdx.x; e < hi; e += (int)blockDim.x) {
        if (ldnt(keep + e) == 0) continue;
        int r = ldnt(xr + e);
        int c = ldnt(xc + e);
        float v = ldntf(xv + e) * INV_KEEP;
        int pos = atomicAdd(&cnt[r >> 8], 1);
        out[pos] = make_float2(v, __uint_as_float(((unsigned)c << 8) | (unsigned)(r & (BROWS - 1))));
    }
}

__global__ __launch_bounds__(256) void partition_a_kernel(
    const float* __restrict__ av, const int* __restrict__ ar,
    const int* __restrict__ ac,
    int* __restrict__ bcur, float2* __restrict__ out, int nnz)
{
    __shared__ int cnt[NBUCKET];
    const int chunk = (nnz + (int)gridDim.x - 1) / (int)gridDim.x;
    const int lo = (int)blockIdx.x * chunk;
    const int hi = min(lo + chunk, nnz);

    for (int k = threadIdx.x; k < NBUCKET; k += blockDim.x) cnt[k] = 0;
    __syncthreads();
    for (int e = lo + (int)threadIdx.x; e < hi; e += (int)blockDim.x)
        atomicAdd(&cnt[ldnt(ar + e) >> 8], 1);
    __syncthreads();
    for (int k = threadIdx.x; k < NBUCKET; k += blockDim.x) {
        int n = cnt[k];
        cnt[k] = (n > 0) ? atomicAdd(&bcur[k * BCPAD], n) : 0;
    }
    __syncthreads();
    for (int e = lo + (int)threadIdx.x; e < hi; e += (int)blockDim.x) {
        int r = ldnt(ar + e);
        int c = ldnt(ac + e);
        float v = ldntf(av + e);
        int pos = atomicAdd(&cnt[r >> 8], 1);
        out[pos] = make_float2(v, __uint_as_float(((unsigned)c << 8) | (unsigned)(r & (BROWS - 1))));
    }
}

// ======================= in-place per-bucket row-grouping =======================

template <int CAP>
__global__ __launch_bounds__(256) void reorder_kernel(
    const int* __restrict__ start, float2* __restrict__ data)
{
    __shared__ float2 recs[CAP];
    __shared__ int curs[BROWS];
    const int b = blockIdx.x;
    const int brow0 = b * BROWS;
    const int rows_n = min(BROWS, N_NODES - brow0);
    const int base = start[brow0];
    int size = start[brow0 + rows_n] - base;
    if (size > CAP) size = CAP;   // statistical guard; prevents corruption

    for (int r = threadIdx.x; r < rows_n; r += blockDim.x)
        curs[r] = start[brow0 + r];
    for (int i = threadIdx.x; i < size; i += blockDim.x)
        recs[i] = data[base + i];
    __syncthreads();
    for (int i = threadIdx.x; i < size; i += blockDim.x) {
        float2 rec = recs[i];
        unsigned u = __float_as_uint(rec.y);
        int row = (int)(u & (BROWS - 1));
        int col = (int)(u >> 8);
        int pos = atomicAdd(&curs[row], 1);
        data[pos] = make_float2(rec.x, __int_as_float(col));
    }
}

// ======================= SpMM (one wave per row, MLP-unrolled) =======================

__global__ __launch_bounds__(256) void spmm1_csr_kernel(
    const int* __restrict__ xs_start, const float2* __restrict__ xs,
    const float* __restrict__ W, __hip_bfloat16* __restrict__ h)
{
    const int wave = (int)((blockIdx.x * blockDim.x + threadIdx.x) >> 6);
    const int lane = threadIdx.x & 63;
    if (wave >= N_NODES) return;

    const int s = xs_start[wave];
    const int e = xs_start[wave + 1];
    float acc = 0.0f;
    int j = s;
    for (; j + 4 <= e; j += 4) {
        float2 p0 = xs[j + 0];
        float2 p1 = xs[j + 1];
        float2 p2 = xs[j + 2];
        float2 p3 = xs[j + 3];
        float g0 = W[__float_as_int(p0.y) * OUT_DIM + lane];
        float g1 = W[__float_as_int(p1.y) * OUT_DIM + lane];
        float g2 = W[__float_as_int(p2.y) * OUT_DIM + lane];
        float g3 = W[__float_as_int(p3.y) * OUT_DIM + lane];
        acc += p0.x * g0;
        acc += p1.x * g1;
        acc += p2.x * g2;
        acc += p3.x * g3;
    }
    for (; j < e; ++j) {
        float2 p = xs[j];
        acc += p.x * W[__float_as_int(p.y) * OUT_DIM + lane];
    }
    h[(size_t)wave * OUT_DIM + lane] = __float2bfloat16(acc);
}

__global__ __launch_bounds__(256) void spmm2_csr_kernel(
    const int* __restrict__ as_start, const float2* __restrict__ as,
    const __hip_bfloat16* __restrict__ h, float* __restrict__ out)
{
    const int wave = (int)((blockIdx.x * blockDim.x + threadIdx.x) >> 6);
    const int lane = threadIdx.x & 63;
    if (wave >= N_NODES) return;

    const int s = as_start[wave];
    const int e = as_start[wave + 1];
    float acc = 0.0f;
    int j = s;
    for (; j + 8 <= e; j += 8) {
        float2 p0 = as[j + 0];
        float2 p1 = as[j + 1];
        float2 p2 = as[j + 2];
        float2 p3 = as[j + 3];
        float2 p4 = as[j + 4];
        float2 p5 = as[j + 5];
        float2 p6 = as[j + 6];
        float2 p7 = as[j + 7];
        float g0 = __bfloat162float(h[(size_t)__float_as_int(p0.y) * OUT_DIM + lane]);
        float g1 = __bfloat162float(h[(size_t)__float_as_int(p1.y) * OUT_DIM + lane]);
        float g2 = __bfloat162float(h[(size_t)__float_as_int(p2.y) * OUT_DIM + lane]);
        float g3 = __bfloat162float(h[(size_t)__float_as_int(p3.y) * OUT_DIM + lane]);
        float g4 = __bfloat162float(h[(size_t)__float_as_int(p4.y) * OUT_DIM + lane]);
        float g5 = __bfloat162float(h[(size_t)__float_as_int(p5.y) * OUT_DIM + lane]);
        float g6 = __bfloat162float(h[(size_t)__float_as_int(p6.y) * OUT_DIM + lane]);
        float g7 = __bfloat162float(h[(size_t)__float_as_int(p7.y) * OUT_DIM + lane]);
        acc += p0.x * g0;
        acc += p1.x * g1;
        acc += p2.x * g2;
        acc += p3.x * g3;
        acc += p4.x * g4;
        acc += p5.x * g5;
        acc += p6.x * g6;
        acc += p7.x * g7;
    }
    for (; j < e; ++j) {
        float2 p = as[j];
        acc += p.x * __bfloat162float(h[(size_t)__float_as_int(p.y) * OUT_DIM + lane]);
    }
    out[(size_t)wave * OUT_DIM + lane] = acc > 0.0f ? acc : 0.0f;
}

// ======================= fallback (atomic) path =======================

__global__ __launch_bounds__(256) void spmm1_atomic_kernel(
    const float* __restrict__ x_vals, const int* __restrict__ x_rows,
    const int* __restrict__ x_cols, const int* __restrict__ keep,
    const float* __restrict__ W, float* __restrict__ h, int nnz)
{
    const int lane   = threadIdx.x & 63;
    const int group  = (int)((blockIdx.x * blockDim.x + threadIdx.x) >> 6);
    const int stride = (int)((gridDim.x * blockDim.x) >> 6);
    for (int e = group; e < nnz; e += stride) {
        float v = (keep[e] != 0) ? x_vals[e] * INV_KEEP : 0.0f;
        if (v != 0.0f)
            atomicAdd(&h[(size_t)x_rows[e] * OUT_DIM + lane],
                      v * W[x_cols[e] * OUT_DIM + lane]);
    }
}

__global__ __launch_bounds__(256) void spmm2_atomic_kernel(
    const float* __restrict__ adj_vals, const int* __restrict__ adj_rows,
    const int* __restrict__ adj_cols, const float* __restrict__ h,
    float* __restrict__ out, int nnz)
{
    const int lane   = threadIdx.x & 63;
    const int group  = (int)((blockIdx.x * blockDim.x + threadIdx.x) >> 6);
    const int stride = (int)((gridDim.x * blockDim.x) >> 6);
    for (int e = group; e < nnz; e += stride) {
        atomicAdd(&out[(size_t)adj_rows[e] * OUT_DIM + lane],
                  adj_vals[e] * h[(size_t)adj_cols[e] * OUT_DIM + lane]);
    }
}

__global__ __launch_bounds__(256) void relu_kernel(float* __restrict__ out, int n)
{
    int i = (int)(blockIdx.x * blockDim.x + threadIdx.x);
    if (i < n) {
        float v = out[i];
        out[i] = v > 0.0f ? v : 0.0f;
    }
}

// ======================= launch =======================

extern "C" void kernel_launch(void* const* d_in, const int* in_sizes, int n_in,
                              void* d_out, int out_size, void* d_ws, size_t ws_size,
                              hipStream_t stream)
{
    const float* x_vals   = (const float*)d_in[0];
    const int*   x_rows   = (const int*)d_in[1];
    const int*   x_cols   = (const int*)d_in[2];
    const float* adj_vals = (const float*)d_in[3];
    const int*   adj_rows = (const int*)d_in[4];
    const int*   adj_cols = (const int*)d_in[5];
    const float* W        = (const float*)d_in[6];
    const int*   keep     = (const int*)d_in[7];

    const int x_nnz = in_sizes[0];
    const int a_nnz = in_sizes[3];

    float* out = (float*)d_out;

    // workspace layout (8B-aligned chunks first)
    char* ws = (char*)d_ws;
    size_t off = 0;
    float2* xs = (float2*)(ws + off);            off += (size_t)x_nnz * 8;           // 12.8 MB
    float2* as = (float2*)(ws + off);            off += (size_t)a_nnz * 8;           // 25.6 MB
    __hip_bfloat16* hb = (__hip_bfloat16*)(ws + off); off += (size_t)N_NODES * OUT_DIM * 2; // 12.8 MB
    int* counts_x = (int*)(ws + off);            off += (size_t)N_NODES * 4;
    int* counts_a = (int*)(ws + off);            off += (size_t)N_NODES * 4;
    int* x_start  = (int*)(ws + off);            off += (size_t)(N_NODES + 1) * 4;
    int* a_start  = (int*)(ws + off);            off += (size_t)(N_NODES + 1) * 4;
    int* blocksums = (int*)(ws + off);           off += (size_t)2 * ((N_NODES + SCAN_BE - 1) / SCAN_BE) * 4;
    int* bcx = (int*)(ws + off);                 off += (size_t)NBUCKET * BCPAD * 4;
    int* bca = (int*)(ws + off);                 off += (size_t)NBUCKET * BCPAD * 4;
    const size_t needed = off;

    const int nb = (N_NODES + SCAN_BE - 1) / SCAN_BE;   // scan blocks per array (<=128)

    if (ws_size >= needed) {
        // -------- bucket-CSR path --------
        hipMemsetAsync(counts_x, 0, (size_t)2 * N_NODES * 4, stream);

        hist_kernel<<<1024, 256, 0, stream>>>(x_rows, keep, counts_x, x_nnz);
        hist_kernel<<<1024, 256, 0, stream>>>(adj_rows, (const int*)nullptr, counts_a, a_nnz);

        scan_pass1_kernel<<<2 * nb, 256, 0, stream>>>(counts_x, counts_a, blocksums, nb);
        scan_pass2_kernel<<<1, 256, 0, stream>>>(blocksums, nb);
        scan_pass3_kernel<<<2 * nb, 256, 0, stream>>>(counts_x, x_start, counts_a, a_start,
                                                      blocksums, nb);

        init_bcursor_kernel<<<1, 512, 0, stream>>>(x_start, a_start, bcx, bca);

        partition_x_kernel<<<PART_BLOCKS, 256, 0, stream>>>(x_vals, x_rows, x_cols, keep,
                                                            bcx, xs, x_nnz);
        partition_a_kernel<<<PART_BLOCKS, 256, 0, stream>>>(adj_vals, adj_rows, adj_cols,
                                                            bca, as, a_nnz);

        reorder_kernel<X_CAP><<<NBUCKET, 256, 0, stream>>>(x_start, xs);
        reorder_kernel<A_CAP><<<NBUCKET, 256, 0, stream>>>(a_start, as);

        const int blocks = (N_NODES * 64 + 255) / 256;  // one wave per row
        spmm1_csr_kernel<<<blocks, 256, 0, stream>>>(x_start, xs, W, hb);
        spmm2_csr_kernel<<<blocks, 256, 0, stream>>>(a_start, as, hb, out);
    } else {
        // -------- fallback: atomic path --------
        float* hf = (float*)d_ws;
        hipMemsetAsync(hf, 0, (size_t)N_NODES * OUT_DIM * 4, stream);
        hipMemsetAsync(out, 0, (size_t)out_size * 4, stream);
        spmm1_atomic_kernel<<<4096, 256, 0, stream>>>(x_vals, x_rows, x_cols, keep, W, hf, x_nnz);
        spmm2_atomic_kernel<<<4096, 256, 0, stream>>>(adj_vals, adj_rows, adj_cols, hf, out, a_nnz);
        relu_kernel<<<(out_size + 255) / 256, 256, 0, stream>>>(out, out_size);
    }
}

// Round 10
// 374.090 us; speedup vs baseline: 5.4162x; 1.3787x over previous
//
#include <hip/hip_runtime.h>
#include <hip/hip_bf16.h>

#define N_NODES 100000
#define IN_DIM 256
#define OUT_DIM 64
#define INV_KEEP 1.1111111111111112f  // 1/0.9

// row-bucket geometry: bucket = 256 consecutive rows
#define BROWS 256
#define NBUCKET ((N_NODES + BROWS - 1) / BROWS)   // 391
#define BCPAD 16     // pad bucket cursors to one 64B line (same-line atomic serialization)
#define A_CAP 9728   // max records/bucket (mean 8184, sigma 90 -> +17 sigma)
#define X_CAP 5120   // mean ~3680, sigma 60 -> +24 sigma

#define PART_BLOCKS 256   // partition blocks: block-private write ranges

__device__ __forceinline__ int   ldnt (const int* p)   { return __builtin_nontemporal_load(p); }
__device__ __forceinline__ float ldntf(const float* p) { return __builtin_nontemporal_load(p); }

// ======================= bucket histogram (LDS-aggregated) =======================
// 391 counters in LDS per block; one global atomic per (block,bucket).

__global__ __launch_bounds__(256) void bucket_hist_kernel(
    const int* __restrict__ rows, const int* __restrict__ keep,
    int* __restrict__ bcnt, int nnz)
{
    __shared__ int cnt[NBUCKET];
    const int chunk = (nnz + (int)gridDim.x - 1) / (int)gridDim.x;
    const int lo = (int)blockIdx.x * chunk;
    const int hi = min(lo + chunk, nnz);

    for (int k = threadIdx.x; k < NBUCKET; k += blockDim.x) cnt[k] = 0;
    __syncthreads();
    if (keep) {
        for (int e = lo + (int)threadIdx.x; e < hi; e += (int)blockDim.x)
            if (ldnt(keep + e) != 0) atomicAdd(&cnt[ldnt(rows + e) >> 8], 1);
    } else {
        for (int e = lo + (int)threadIdx.x; e < hi; e += (int)blockDim.x)
            atomicAdd(&cnt[ldnt(rows + e) >> 8], 1);
    }
    __syncthreads();
    for (int k = threadIdx.x; k < NBUCKET; k += blockDim.x) {
        int n = cnt[k];
        if (n > 0) atomicAdd(&bcnt[k], n);
    }
}

// ======================= bucket scan (391 elems, trivial) =======================
// block 0: x array, block 1: a array. Writes bstart[0..NBUCKET] and seeds the
// padded partition cursors.

__global__ __launch_bounds__(512) void bucket_scan_kernel(
    const int* __restrict__ bcnt_x, const int* __restrict__ bcnt_a,
    int* __restrict__ bstart_x, int* __restrict__ bstart_a,
    int* __restrict__ bcurx, int* __restrict__ bcura)
{
    const int* c  = blockIdx.x ? bcnt_a : bcnt_x;
    int* bs       = blockIdx.x ? bstart_a : bstart_x;
    int* bc       = blockIdx.x ? bcura : bcurx;
    __shared__ int sc[512];
    const int t = threadIdx.x;
    sc[t] = (t < NBUCKET) ? c[t] : 0;
    __syncthreads();
    for (int off = 1; off < 512; off <<= 1) {
        int v = (t >= off) ? sc[t - off] : 0;
        __syncthreads();
        sc[t] += v;
        __syncthreads();
    }
    if (t < NBUCKET) {
        int excl = (t > 0) ? sc[t - 1] : 0;
        bs[t] = excl;
        bc[t * BCPAD] = excl;
        if (t == NBUCKET - 1) bs[NBUCKET] = sc[t];
    }
}

// ======================= partition: block-aggregated 2-pass bucket append =======================

__global__ __launch_bounds__(256) void partition_x_kernel(
    const float* __restrict__ xv, const int* __restrict__ xr,
    const int* __restrict__ xc, const int* __restrict__ keep,
    int* __restrict__ bcur, float2* __restrict__ out, int nnz)
{
    __shared__ int cnt[NBUCKET];
    const int chunk = (nnz + (int)gridDim.x - 1) / (int)gridDim.x;
    const int lo = (int)blockIdx.x * chunk;
    const int hi = min(lo + chunk, nnz);

    for (int k = threadIdx.x; k < NBUCKET; k += blockDim.x) cnt[k] = 0;
    __syncthreads();
    for (int e = lo + (int)threadIdx.x; e < hi; e += (int)blockDim.x)
        if (ldnt(keep + e) != 0) atomicAdd(&cnt[ldnt(xr + e) >> 8], 1);
    __syncthreads();
    for (int k = threadIdx.x; k < NBUCKET; k += blockDim.x) {
        int n = cnt[k];
        cnt[k] = (n > 0) ? atomicAdd(&bcur[k * BCPAD], n) : 0;
    }
    __syncthreads();
    for (int e = lo + (int)threadIdx.x; e < hi; e += (int)blockDim.x) {
        if (ldnt(keep + e) == 0) continue;
        int r = ldnt(xr + e);
        int c = ldnt(xc + e);
        float v = ldntf(xv + e) * INV_KEEP;
        int pos = atomicAdd(&cnt[r >> 8], 1);
        out[pos] = make_float2(v, __uint_as_float(((unsigned)c << 8) | (unsigned)(r & (BROWS - 1))));
    }
}

__global__ __launch_bounds__(256) void partition_a_kernel(
    const float* __restrict__ av, const int* __restrict__ ar,
    const int* __restrict__ ac,
    int* __restrict__ bcur, float2* __restrict__ out, int nnz)
{
    __shared__ int cnt[NBUCKET];
    const int chunk = (nnz + (int)gridDim.x - 1) / (int)gridDim.x;
    const int lo = (int)blockIdx.x * chunk;
    const int hi = min(lo + chunk, nnz);

    for (int k = threadIdx.x; k < NBUCKET; k += blockDim.x) cnt[k] = 0;
    __syncthreads();
    for (int e = lo + (int)threadIdx.x; e < hi; e += (int)blockDim.x)
        atomicAdd(&cnt[ldnt(ar + e) >> 8], 1);
    __syncthreads();
    for (int k = threadIdx.x; k < NBUCKET; k += blockDim.x) {
        int n = cnt[k];
        cnt[k] = (n > 0) ? atomicAdd(&bcur[k * BCPAD], n) : 0;
    }
    __syncthreads();
    for (int e = lo + (int)threadIdx.x; e < hi; e += (int)blockDim.x) {
        int r = ldnt(ar + e);
        int c = ldnt(ac + e);
        float v = ldntf(av + e);
        int pos = atomicAdd(&cnt[r >> 8], 1);
        out[pos] = make_float2(v, __uint_as_float(((unsigned)c << 8) | (unsigned)(r & (BROWS - 1))));
    }
}

// ======================= reorder: in-bucket row-grouping + per-row start =======================
// One block per bucket: load records to LDS, LDS-count per-row occupancy,
// block-scan 256 counters -> per-row starts (written to global start[], 1KB
// coalesced), then place records row-grouped.

template <int CAP>
__global__ __launch_bounds__(256) void reorder_kernel(
    const int* __restrict__ bstart, float2* __restrict__ data,
    int* __restrict__ start)
{
    __shared__ float2 recs[CAP];
    __shared__ int rcnt[BROWS];
    __shared__ int sc[BROWS];
    __shared__ int curs[BROWS];
    const int b = blockIdx.x;
    const int brow0 = b * BROWS;
    const int rows_n = min(BROWS, N_NODES - brow0);
    const int base = bstart[b];
    int size = bstart[b + 1] - base;
    if (size > CAP) size = CAP;   // statistical guard; prevents corruption
    const int t = threadIdx.x;

    rcnt[t] = 0;
    __syncthreads();
    for (int i = t; i < size; i += 256) {
        float2 rec = data[base + i];
        recs[i] = rec;
        atomicAdd(&rcnt[__float_as_uint(rec.y) & (BROWS - 1)], 1);
    }
    __syncthreads();
    sc[t] = rcnt[t];
    __syncthreads();
    for (int off = 1; off < 256; off <<= 1) {
        int v = (t >= off) ? sc[t - off] : 0;
        __syncthreads();
        sc[t] += v;
        __syncthreads();
    }
    int excl = (t > 0) ? sc[t - 1] : 0;
    curs[t] = base + excl;
    if (t < rows_n) start[brow0 + t] = base + excl;
    if (brow0 + rows_n == N_NODES && t == rows_n - 1) start[N_NODES] = base + size;
    __syncthreads();
    for (int i = t; i < size; i += 256) {
        float2 rec = recs[i];
        unsigned u = __float_as_uint(rec.y);
        int pos = atomicAdd(&curs[u & (BROWS - 1)], 1);
        data[pos] = make_float2(rec.x, __int_as_float((int)(u >> 8)));
    }
}

// ======================= SpMM (one wave per row, MLP-unrolled) =======================

__global__ __launch_bounds__(256) void spmm1_csr_kernel(
    const int* __restrict__ xs_start, const float2* __restrict__ xs,
    const float* __restrict__ W, __hip_bfloat16* __restrict__ h)
{
    const int wave = (int)((blockIdx.x * blockDim.x + threadIdx.x) >> 6);
    const int lane = threadIdx.x & 63;
    if (wave >= N_NODES) return;

    const int s = xs_start[wave];
    const int e = xs_start[wave + 1];
    float acc = 0.0f;
    int j = s;
    for (; j + 4 <= e; j += 4) {
        float2 p0 = xs[j + 0];
        float2 p1 = xs[j + 1];
        float2 p2 = xs[j + 2];
        float2 p3 = xs[j + 3];
        float g0 = W[__float_as_int(p0.y) * OUT_DIM + lane];
        float g1 = W[__float_as_int(p1.y) * OUT_DIM + lane];
        float g2 = W[__float_as_int(p2.y) * OUT_DIM + lane];
        float g3 = W[__float_as_int(p3.y) * OUT_DIM + lane];
        acc += p0.x * g0;
        acc += p1.x * g1;
        acc += p2.x * g2;
        acc += p3.x * g3;
    }
    for (; j < e; ++j) {
        float2 p = xs[j];
        acc += p.x * W[__float_as_int(p.y) * OUT_DIM + lane];
    }
    h[(size_t)wave * OUT_DIM + lane] = __float2bfloat16(acc);
}

__global__ __launch_bounds__(256) void spmm2_csr_kernel(
    const int* __restrict__ as_start, const float2* __restrict__ as,
    const __hip_bfloat16* __restrict__ h, float* __restrict__ out)
{
    const int wave = (int)((blockIdx.x * blockDim.x + threadIdx.x) >> 6);
    const int lane = threadIdx.x & 63;
    if (wave >= N_NODES) return;

    const int s = as_start[wave];
    const int e = as_start[wave + 1];
    float acc = 0.0f;
    int j = s;
    for (; j + 8 <= e; j += 8) {
        float2 p0 = as[j + 0];
        float2 p1 = as[j + 1];
        float2 p2 = as[j + 2];
        float2 p3 = as[j + 3];
        float2 p4 = as[j + 4];
        float2 p5 = as[j + 5];
        float2 p6 = as[j + 6];
        float2 p7 = as[j + 7];
        float g0 = __bfloat162float(h[(size_t)__float_as_int(p0.y) * OUT_DIM + lane]);
        float g1 = __bfloat162float(h[(size_t)__float_as_int(p1.y) * OUT_DIM + lane]);
        float g2 = __bfloat162float(h[(size_t)__float_as_int(p2.y) * OUT_DIM + lane]);
        float g3 = __bfloat162float(h[(size_t)__float_as_int(p3.y) * OUT_DIM + lane]);
        float g4 = __bfloat162float(h[(size_t)__float_as_int(p4.y) * OUT_DIM + lane]);
        float g5 = __bfloat162float(h[(size_t)__float_as_int(p5.y) * OUT_DIM + lane]);
        float g6 = __bfloat162float(h[(size_t)__float_as_int(p6.y) * OUT_DIM + lane]);
        float g7 = __bfloat162float(h[(size_t)__float_as_int(p7.y) * OUT_DIM + lane]);
        acc += p0.x * g0;
        acc += p1.x * g1;
        acc += p2.x * g2;
        acc += p3.x * g3;
        acc += p4.x * g4;
        acc += p5.x * g5;
        acc += p6.x * g6;
        acc += p7.x * g7;
    }
    for (; j < e; ++j) {
        float2 p = as[j];
        acc += p.x * __bfloat162float(h[(size_t)__float_as_int(p.y) * OUT_DIM + lane]);
    }
    out[(size_t)wave * OUT_DIM + lane] = acc > 0.0f ? acc : 0.0f;
}

// ======================= fallback (atomic) path =======================

__global__ __launch_bounds__(256) void spmm1_atomic_kernel(
    const float* __restrict__ x_vals, const int* __restrict__ x_rows,
    const int* __restrict__ x_cols, const int* __restrict__ keep,
    const float* __restrict__ W, float* __restrict__ h, int nnz)
{
    const int lane   = threadIdx.x & 63;
    const int group  = (int)((blockIdx.x * blockDim.x + threadIdx.x) >> 6);
    const int stride = (int)((gridDim.x * blockDim.x) >> 6);
    for (int e = group; e < nnz; e += stride) {
        float v = (keep[e] != 0) ? x_vals[e] * INV_KEEP : 0.0f;
        if (v != 0.0f)
            atomicAdd(&h[(size_t)x_rows[e] * OUT_DIM + lane],
                      v * W[x_cols[e] * OUT_DIM + lane]);
    }
}

__global__ __launch_bounds__(256) void spmm2_atomic_kernel(
    const float* __restrict__ adj_vals, const int* __restrict__ adj_rows,
    const int* __restrict__ adj_cols, const float* __restrict__ h,
    float* __restrict__ out, int nnz)
{
    const int lane   = threadIdx.x & 63;
    const int group  = (int)((blockIdx.x * blockDim.x + threadIdx.x) >> 6);
    const int stride = (int)((gridDim.x * blockDim.x) >> 6);
    for (int e = group; e < nnz; e += stride) {
        atomicAdd(&out[(size_t)adj_rows[e] * OUT_DIM + lane],
                  adj_vals[e] * h[(size_t)adj_cols[e] * OUT_DIM + lane]);
    }
}

__global__ __launch_bounds__(256) void relu_kernel(float* __restrict__ out, int n)
{
    int i = (int)(blockIdx.x * blockDim.x + threadIdx.x);
    if (i < n) {
        float v = out[i];
        out[i] = v > 0.0f ? v : 0.0f;
    }
}

// ======================= launch =======================

extern "C" void kernel_launch(void* const* d_in, const int* in_sizes, int n_in,
                              void* d_out, int out_size, void* d_ws, size_t ws_size,
                              hipStream_t stream)
{
    const float* x_vals   = (const float*)d_in[0];
    const int*   x_rows   = (const int*)d_in[1];
    const int*   x_cols   = (const int*)d_in[2];
    const float* adj_vals = (const float*)d_in[3];
    const int*   adj_rows = (const int*)d_in[4];
    const int*   adj_cols = (const int*)d_in[5];
    const float* W        = (const float*)d_in[6];
    const int*   keep     = (const int*)d_in[7];

    const int x_nnz = in_sizes[0];
    const int a_nnz = in_sizes[3];

    float* out = (float*)d_out;

    // workspace layout (8B-aligned chunks first)
    char* ws = (char*)d_ws;
    size_t off = 0;
    float2* xs = (float2*)(ws + off);            off += (size_t)x_nnz * 8;           // 12.8 MB
    float2* as = (float2*)(ws + off);            off += (size_t)a_nnz * 8;           // 25.6 MB
    __hip_bfloat16* hb = (__hip_bfloat16*)(ws + off); off += (size_t)N_NODES * OUT_DIM * 2; // 12.8 MB
    int* x_start  = (int*)(ws + off);            off += (size_t)(N_NODES + 1) * 4;
    int* a_start  = (int*)(ws + off);            off += (size_t)(N_NODES + 1) * 4;
    int* bcnt_x   = (int*)(ws + off);            off += (size_t)NBUCKET * 4;
    int* bcnt_a   = (int*)(ws + off);            off += (size_t)NBUCKET * 4;   // adjacent: one memset
    int* bstart_x = (int*)(ws + off);            off += (size_t)(NBUCKET + 1) * 4;
    int* bstart_a = (int*)(ws + off);            off += (size_t)(NBUCKET + 1) * 4;
    int* bcurx    = (int*)(ws + off);            off += (size_t)NBUCKET * BCPAD * 4;
    int* bcura    = (int*)(ws + off);            off += (size_t)NBUCKET * BCPAD * 4;
    const size_t needed = off;

    if (ws_size >= needed) {
        // -------- bucket-CSR path --------
        hipMemsetAsync(bcnt_x, 0, (size_t)2 * NBUCKET * 4, stream);

        bucket_hist_kernel<<<512, 256, 0, stream>>>(x_rows, keep, bcnt_x, x_nnz);
        bucket_hist_kernel<<<512, 256, 0, stream>>>(adj_rows, (const int*)nullptr, bcnt_a, a_nnz);

        bucket_scan_kernel<<<2, 512, 0, stream>>>(bcnt_x, bcnt_a, bstart_x, bstart_a,
                                                  bcurx, bcura);

        partition_x_kernel<<<PART_BLOCKS, 256, 0, stream>>>(x_vals, x_rows, x_cols, keep,
                                                            bcurx, xs, x_nnz);
        partition_a_kernel<<<PART_BLOCKS, 256, 0, stream>>>(adj_vals, adj_rows, adj_cols,
                                                            bcura, as, a_nnz);

        reorder_kernel<X_CAP><<<NBUCKET, 256, 0, stream>>>(bstart_x, xs, x_start);
        reorder_kernel<A_CAP><<<NBUCKET, 256, 0, stream>>>(bstart_a, as, a_start);

        const int blocks = (N_NODES * 64 + 255) / 256;  // one wave per row
        spmm1_csr_kernel<<<blocks, 256, 0, stream>>>(x_start, xs, W, hb);
        spmm2_csr_kernel<<<blocks, 256, 0, stream>>>(a_start, as, hb, out);
    } else {
        // -------- fallback: atomic path --------
        float* hf = (float*)d_ws;
        hipMemsetAsync(hf, 0, (size_t)N_NODES * OUT_DIM * 4, stream);
        hipMemsetAsync(out, 0, (size_t)out_size * 4, stream);
        spmm1_atomic_kernel<<<4096, 256, 0, stream>>>(x_vals, x_rows, x_cols, keep, W, hf, x_nnz);
        spmm2_atomic_kernel<<<4096, 256, 0, stream>>>(adj_vals, adj_rows, adj_cols, hf, out, a_nnz);
        relu_kernel<<<(out_size + 255) / 256, 256, 0, stream>>>(out, out_size);
    }
}